// Round 1
// baseline (8097.234 us; speedup 1.0000x reference)
//
#include <hip/hip_runtime.h>

// ---------------------------------------------------------------------------
// LSTM B=32, S=2048, E=512, H=512 (gates 4H=2048), fp32 in/out.
//   prep_kernel : permuted bias, zero tagged-h planes, lengths->floats.
//   xproj_gemm  : xp[t][b][n''] bf16 = x @ W_ih^T + bias (split-bf16 MFMA).
//                 n'' = (u>>2)*16 + (u&3)*4 + g  -> the 4 gate pre-acts of a
//                 (b,u) pair are CONTIGUOUS (one 8B load in the recurrence).
//   lstm_rec    : persistent, 64 WGs x 256 thr = two independent 32-WG clubs
//                 (one per batch half). WG = 16 units x 16 batches. W_hh in
//                 VGPRs (bf16 hi/lo split, 3-term MFMA).
//
//   R5 change: TAG-IN-DATA exchange. h entries are 8B single-copy-atomic
//   words { tag = step | packed hi/lo bf16 }. Producer: ONE relaxed agent
//   8B store (no vmcnt drain, no flag, no ordering asm). Consumer: polls the
//   data directly; when tag==t the payload is already in registers -> the
//   poll's last iteration IS the staging load. Collapses the previous
//   3-serialized-round-trips/step (drain, flag->poll, h load) to ~1, and
//   drops 2 of the 4 per-step barriers.
//   Entries hold ONE unit each, so thread tid loads units {tid, tid+256};
//   a K-permutation pi(2j)=j, pi(2j+1)=j+256 is applied to BOTH the h LDS
//   planes and the W_hh register fragments (bijective K reorder == same dot
//   product), keeping the LDS swizzle and MFMA structure identical.
// ---------------------------------------------------------------------------

typedef __attribute__((ext_vector_type(8))) __bf16 bf16x8;
typedef __attribute__((ext_vector_type(8))) short short8;
typedef __attribute__((ext_vector_type(4))) float floatx4;
typedef __attribute__((ext_vector_type(2))) unsigned uint32x2;

// ws layout (bytes)
#define XP_OFF   0ull
#define XP_BYTES (2048ull * 32ull * 2048ull * 2ull)   // 268,435,456
#define HPK_OFF  (XP_OFF + XP_BYTES)                  // 2 bufs x 32x512 x 8B
#define HPK_BYTES (2ull * 16384ull * 8ull)
#define BIAS_OFF (HPK_OFF + HPK_BYTES)
#define WS_NEED  (BIAS_OFF + 8192ull)

// d_out layout (fp32): out[32][2048][1][512], lengths[32], hidden[1][32][512]
#define LEN_OFF_F    33554432
#define HIDDEN_OFF_F 33554464

__device__ inline float sigm(float x) { return 1.f / (1.f + __expf(-x)); }
__device__ inline float tanh_(float x) {
  float e = __expf(-2.f * fabsf(x));
  float r = (1.f - e) / (1.f + e);
  return x >= 0.f ? r : -r;
}

__device__ inline void cvt_hilo8(const float* v, bf16x8& hi, bf16x8& lo) {
#pragma unroll
  for (int i = 0; i < 8; ++i) {
    __bf16 h = (__bf16)v[i];
    hi[i] = h;
    lo[i] = (__bf16)(v[i] - (float)h);
  }
}

__device__ inline float bf16f(unsigned short u) {
  union { unsigned u; float f; } c; c.u = ((unsigned)u) << 16; return c.f;
}

// ---------------------------------------------------------------------------
__global__ __launch_bounds__(256) void prep_kernel(
    const float* __restrict__ bih, const float* __restrict__ bhh,
    const int* __restrict__ len, float* __restrict__ biasp,
    unsigned long long* __restrict__ hpk, float* __restrict__ outf) {
  const int tid = threadIdx.x;
  for (int i = tid; i < 2048; i += 256) {
    // n'' = ug4*16 + ul*4 + g  ->  W row = g*512 + ug4*4 + ul
    int rowg = (i & 3) * 512 + (i >> 4) * 4 + ((i >> 2) & 3);
    biasp[i] = bih[rowg] + bhh[rowg];
  }
  // buf0: tag 0 == "h input for step 0" (h=0). buf1: tag 0 is never a valid
  // odd-step tag, so it reads as "not ready".
  for (int i = tid; i < 32768; i += 256) hpk[i] = 0ull;
  if (tid < 32) outf[LEN_OFF_F + tid] = (float)len[tid];
}

// ---------------------------------------------------------------------------
// xp GEMM: M=65536 (b*2048+s), N=2048 (n''), K=512. Tile 64x64, BK=32.
__global__ __launch_bounds__(256) void xproj_gemm(
    const float* __restrict__ x, const float* __restrict__ Wih,
    const float* __restrict__ biasp, __bf16* __restrict__ xp) {
  __shared__ short Ash[64 * 40], Asl[64 * 40], Bsh[64 * 40], Bsl[64 * 40];
  const int tid = threadIdx.x;
  const int w = tid >> 6, lane = tid & 63, ln = lane & 15, kq = lane >> 4;
  const int ntile = blockIdx.x & 31, mtile = blockIdx.x >> 5;
  const int srow = tid >> 2, sseg = tid & 3;

  const size_t a_base = (size_t)(mtile * 64 + srow) * 512 + sseg * 8;
  const int np_s = ntile * 64 + srow;
  const int rowg = (np_s & 3) * 512 + (np_s >> 4) * 4 + ((np_s >> 2) & 3);
  const size_t b_base = (size_t)rowg * 512 + sseg * 8;

  floatx4 acc[4] = {{0,0,0,0},{0,0,0,0},{0,0,0,0},{0,0,0,0}};

  for (int k0 = 0; k0 < 512; k0 += 32) {
    floatx4 a0 = *(const floatx4*)(x + a_base + k0);
    floatx4 a1 = *(const floatx4*)(x + a_base + k0 + 4);
    floatx4 b0 = *(const floatx4*)(Wih + b_base + k0);
    floatx4 b1 = *(const floatx4*)(Wih + b_base + k0 + 4);
    __syncthreads();
    {
      float va[8] = {a0[0],a0[1],a0[2],a0[3],a1[0],a1[1],a1[2],a1[3]};
      bf16x8 hi, lo; cvt_hilo8(va, hi, lo);
      *(short8*)&Ash[srow * 40 + sseg * 8] = __builtin_bit_cast(short8, hi);
      *(short8*)&Asl[srow * 40 + sseg * 8] = __builtin_bit_cast(short8, lo);
      float vb[8] = {b0[0],b0[1],b0[2],b0[3],b1[0],b1[1],b1[2],b1[3]};
      cvt_hilo8(vb, hi, lo);
      *(short8*)&Bsh[srow * 40 + sseg * 8] = __builtin_bit_cast(short8, hi);
      *(short8*)&Bsl[srow * 40 + sseg * 8] = __builtin_bit_cast(short8, lo);
    }
    __syncthreads();
    bf16x8 ah = __builtin_bit_cast(bf16x8, *(const short8*)&Ash[(16 * w + ln) * 40 + kq * 8]);
    bf16x8 al = __builtin_bit_cast(bf16x8, *(const short8*)&Asl[(16 * w + ln) * 40 + kq * 8]);
#pragma unroll
    for (int nt = 0; nt < 4; ++nt) {
      bf16x8 bh = __builtin_bit_cast(bf16x8, *(const short8*)&Bsh[(nt * 16 + ln) * 40 + kq * 8]);
      bf16x8 bl = __builtin_bit_cast(bf16x8, *(const short8*)&Bsl[(nt * 16 + ln) * 40 + kq * 8]);
      acc[nt] = __builtin_amdgcn_mfma_f32_16x16x32_bf16(ah, bh, acc[nt], 0, 0, 0);
      acc[nt] = __builtin_amdgcn_mfma_f32_16x16x32_bf16(al, bh, acc[nt], 0, 0, 0);
      acc[nt] = __builtin_amdgcn_mfma_f32_16x16x32_bf16(ah, bl, acc[nt], 0, 0, 0);
    }
  }
#pragma unroll
  for (int nt = 0; nt < 4; ++nt) {
    const int npg = ntile * 64 + nt * 16 + ln;
    const float bs = biasp[npg];
#pragma unroll
    for (int r = 0; r < 4; ++r) {
      const int m = mtile * 64 + w * 16 + kq * 4 + r;
      const int s = m & 2047, b = m >> 11;
      xp[(size_t)(s * 32 + b) * 2048 + npg] = (__bf16)(acc[nt][r] + bs);
    }
  }
}

// ---------------------------------------------------------------------------
__global__ __launch_bounds__(256, 1) void lstm_rec(
    const float* __restrict__ Whh, const int* __restrict__ lengths,
    const __bf16* __restrict__ xp, float* __restrict__ out,
    float* __restrict__ hid, unsigned long long* __restrict__ hpk) {
  __shared__ short Hh[16 * 512];       // [m][K-pos] bf16 hi, xor-swizzled
  __shared__ short Hl[16 * 512];
  __shared__ float Part[4 * 1088];     // [wave][nt(272 pad)][m][n]

  const int tid = threadIdx.x;
  const int w = tid >> 6, lane = tid & 63, ln = lane & 15, kq = lane >> 4;
  const int bh = blockIdx.x >> 5;      // batch half
  const int ug = blockIdx.x & 31;      // 16-unit group
  const int b0 = bh * 16;

  // Persistent W_hh frags with K-permutation: position 2j <- unit j,
  // position 2j+1 <- unit j+256 (consumer thread tid coalesced-loads units
  // tid and tid+256 and owns contiguous positions 2tid, 2tid+1).
  // Tile nt, lane ln: g=ln&3, ul=ln>>2, unit = ug*16+nt*4+ul, row = g*512+unit.
  bf16x8 whi[4][4], wlo[4][4];
#pragma unroll
  for (int nt = 0; nt < 4; ++nt) {
    const int rowg = (ln & 3) * 512 + (ug * 4 + nt) * 4 + (ln >> 2);
#pragma unroll
    for (int kc = 0; kc < 4; ++kc) {
      const int h0 = w * 64 + kc * 16 + kq * 4;  // (w*128+kc*32+kq*8)/2
      floatx4 f0 = *(const floatx4*)(Whh + (size_t)rowg * 512 + h0);
      floatx4 f1 = *(const floatx4*)(Whh + (size_t)rowg * 512 + h0 + 256);
      float v[8] = {f0[0],f1[0],f0[1],f1[1],f0[2],f1[2],f0[3],f1[3]};
      cvt_hilo8(v, whi[nt][kc], wlo[nt][kc]);
    }
  }

  // Elementwise ownership: 1 (batch,unit) per thread.
  const int m_e = tid >> 4, ue = tid & 15;
  const int b_e = b0 + m_e, u_e = ug * 16 + ue;
  const int lenb = lengths[b_e];
  float cst = 0.f, hcap = 0.f;

  // xp: this thread's 4 gate pre-acts are 8B contiguous (plain cached loads).
  const __bf16* xpb = xp + (size_t)b_e * 2048 + ug * 64 + (ue >> 2) * 16 + (ue & 3) * 4;
  uint32x2 xpcur = *(const uint32x2*)xpb;  // t = 0
  uint32x2 xpnext;

  unsigned long long* pub = hpk + b_e * 512 + u_e;          // + buf*16384
  const unsigned long long* pollb = hpk + b0 * 512 + tid;   // units tid, tid+256

  for (int t = 0; t < 2048; ++t) {
    // xp prefetch for t+1 (in flight across the poll + MFMA phases)
    {
      const int tn = (t + 1 < 2048) ? t + 1 : 2047;
      xpnext = *(const uint32x2*)(xpb + (size_t)tn * 65536);
    }
    // ---- poll-and-load: tag arrives WITH data (one round trip). Each
    // thread waits on its own 32 entries; lanes already complete keep their
    // registers and skip the re-load (masked off). ----
    const unsigned long long* src = pollb + (t & 1) * 16384;
    unsigned long long e[32];
    bool ok = false;
    for (;;) {
      if (!ok) {
#pragma unroll
        for (int k = 0; k < 16; ++k) {
          e[2 * k] = __hip_atomic_load(src + k * 512, __ATOMIC_RELAXED,
                                       __HIP_MEMORY_SCOPE_AGENT);
          e[2 * k + 1] = __hip_atomic_load(src + k * 512 + 256, __ATOMIC_RELAXED,
                                           __HIP_MEMORY_SCOPE_AGENT);
        }
        ok = true;
#pragma unroll
        for (int k = 0; k < 32; ++k)
          ok &= ((unsigned)(e[k] >> 32) == (unsigned)t);
      }
      if (__ballot(!ok) == 0ull) break;
      __builtin_amdgcn_s_sleep(1);
    }
    // ---- unpack hi/lo -> swizzled LDS planes (2-way-free bank pattern).
    // d0 = unit tid (K-pos 2*tid), d1 = unit tid+256 (K-pos 2*tid+1). ----
    {
      const int g = tid >> 2;  // granule of 8 K-positions
#pragma unroll
      for (int k = 0; k < 16; ++k) {
        const unsigned d0 = (unsigned)e[2 * k], d1 = (unsigned)e[2 * k + 1];
        const int d = k * 512 + ((g ^ (k & 7)) * 8) + (tid & 3) * 2;
        *(unsigned*)&Hh[d] = (d0 >> 16) | (d1 & 0xffff0000u);
        *(unsigned*)&Hl[d] = (d0 & 0xffffu) | (d1 << 16);
      }
    }
    __syncthreads();
    // ---- MFMA: M=16 batches x N=16 gate-rows x 4 tiles, wave K-slice ----
    floatx4 acc[4] = {{0,0,0,0},{0,0,0,0},{0,0,0,0},{0,0,0,0}};
#pragma unroll
    for (int kc = 0; kc < 4; ++kc) {
      const int g = w * 16 + kc * 4 + kq;
      const int d = ln * 512 + ((g ^ (ln & 7)) * 8);
      bf16x8 ah = __builtin_bit_cast(bf16x8, *(const short8*)&Hh[d]);
      bf16x8 al = __builtin_bit_cast(bf16x8, *(const short8*)&Hl[d]);
#pragma unroll
      for (int nt = 0; nt < 4; ++nt) {
        acc[nt] = __builtin_amdgcn_mfma_f32_16x16x32_bf16(ah, whi[nt][kc], acc[nt], 0, 0, 0);
        acc[nt] = __builtin_amdgcn_mfma_f32_16x16x32_bf16(al, whi[nt][kc], acc[nt], 0, 0, 0);
        acc[nt] = __builtin_amdgcn_mfma_f32_16x16x32_bf16(ah, wlo[nt][kc], acc[nt], 0, 0, 0);
      }
    }
#pragma unroll
    for (int nt = 0; nt < 4; ++nt)
#pragma unroll
      for (int r4 = 0; r4 < 4; ++r4)
        Part[w * 1088 + nt * 272 + (kq * 4 + r4) * 16 + ln] = acc[nt][r4];
    __syncthreads();
    // ---- reduce + gates + state (all 256 threads, one (b,u) each) ----
    {
      const int pb = (ue >> 2) * 272 + m_e * 16 + (ue & 3) * 4;
      floatx4 p0 = *(const floatx4*)&Part[pb];
      floatx4 p1 = *(const floatx4*)&Part[1088 + pb];
      floatx4 p2 = *(const floatx4*)&Part[2176 + pb];
      floatx4 p3 = *(const floatx4*)&Part[3264 + pb];
      const float xg0 = bf16f((unsigned short)(xpcur[0] & 0xffffu));
      const float xg1 = bf16f((unsigned short)(xpcur[0] >> 16));
      const float xg2 = bf16f((unsigned short)(xpcur[1] & 0xffffu));
      const float xg3 = bf16f((unsigned short)(xpcur[1] >> 16));
      const float pi = xg0 + p0[0] + p1[0] + p2[0] + p3[0];
      const float pf = xg1 + p0[1] + p1[1] + p2[1] + p3[1];
      const float pg = xg2 + p0[2] + p1[2] + p2[2] + p3[2];
      const float po = xg3 + p0[3] + p1[3] + p2[3] + p3[3];
      const float gi_ = sigm(pi), gf = sigm(pf), gg = tanh_(pg), go = sigm(po);
      cst = gf * cst + gi_ * gg;
      const float hv = go * tanh_(cst);
      // publish h: ONE 8B single-copy-atomic store {tag=t+1 | hi/lo bf16}.
      // No drain, no flag: consumers detect readiness from the tag itself.
      const __bf16 hb = (__bf16)hv;
      const __bf16 lb = (__bf16)(hv - (float)hb);
      const unsigned pk =
          ((unsigned)__builtin_bit_cast(unsigned short, hb) << 16) |
          (unsigned)__builtin_bit_cast(unsigned short, lb);
      __hip_atomic_store(pub + ((t + 1) & 1) * 16384,
                         ((unsigned long long)(unsigned)(t + 1) << 32) |
                             (unsigned long long)pk,
                         __ATOMIC_RELAXED, __HIP_MEMORY_SCOPE_AGENT);
      // off-path stores: out now, hid captured in a register
      out[((size_t)b_e * 2048 + t) * 512 + u_e] = (t < lenb) ? hv : 0.f;
      if (t == lenb - 1) hcap = hv;
    }
    xpcur = xpnext;
  }
  hid[b_e * 512 + u_e] = hcap;
}

// ---------------------------------------------------------------------------
extern "C" void kernel_launch(void* const* d_in, const int* in_sizes, int n_in,
                              void* d_out, int out_size, void* d_ws, size_t ws_size,
                              hipStream_t stream) {
  const float* x = (const float*)d_in[0];
  const int* lengths = (const int*)d_in[1];
  const float* Wih = (const float*)d_in[2];
  const float* Whh = (const float*)d_in[3];
  const float* bih = (const float*)d_in[4];
  const float* bhh = (const float*)d_in[5];
  float* outf = (float*)d_out;
  char* ws = (char*)d_ws;
  if (ws_size < WS_NEED) return;

  float* biasp = (float*)(ws + BIAS_OFF);
  __bf16* xp = (__bf16*)(ws + XP_OFF);
  unsigned long long* hpk = (unsigned long long*)(ws + HPK_OFF);

  prep_kernel<<<1, 256, 0, stream>>>(bih, bhh, lengths, biasp, hpk, outf);
  xproj_gemm<<<32768, 256, 0, stream>>>(x, Wih, biasp, xp);
  lstm_rec<<<64, 256, 0, stream>>>(Whh, lengths, xp, outf,
                                   outf + HIDDEN_OFF_F, hpk);
}